// Round 6
// baseline (404.481 us; speedup 1.0000x reference)
//
#include <hip/hip_runtime.h>
#include <hip/hip_bf16.h>
#include <stdint.h>

#define K_DIM 4096
#define M_DIM 8192
#define N_DIM 4096

typedef short bf16x8 __attribute__((ext_vector_type(8)));
typedef float f32x4  __attribute__((ext_vector_type(4)));

__device__ __forceinline__ uint16_t f2bf(float f) {
  uint32_t u = __float_as_uint(f);
  u += 0x7fffu + ((u >> 16) & 1u);   // round-to-nearest-even
  return (uint16_t)(u >> 16);
}

__device__ __forceinline__ float wval(float b0, float b1, float b2, float sg) {
  float mg = (b0 >= 0.f ? 0.5f : 0.f) + (b1 >= 0.f ? 0.25f : 0.f) + (b2 >= 0.f ? 0.125f : 0.f);
  return (sg >= 0.f) ? mg : -mg;
}

__device__ __forceinline__ void gload16(const void* g, void* l) {
  typedef __attribute__((address_space(1))) const uint32_t gu32;
  typedef __attribute__((address_space(3))) uint32_t lu32;
  __builtin_amdgcn_global_load_lds((gu32*)g, (lu32*)l, 16, 0, 0);
}

// ---------- Kernel 1: W^T (bf16) build + transpose + per-block sum/sumsq ----
__global__ __launch_bounds__(256) void build_wt(
    const float* __restrict__ mag, const float* __restrict__ sgn,
    uint16_t* __restrict__ wt, float* __restrict__ psum, float* __restrict__ psumsq)
{
  __shared__ float wl[64][65];
  __shared__ float parts[8];
  const int tid = threadIdx.x;
  const int lr = tid >> 4;   // 0..15
  const int lc = tid & 15;   // 0..15
  const int i0 = blockIdx.y * 64;   // input-dim (K) tile
  const int o0 = blockIdx.x * 64;   // output-dim (N) tile
  const float* m0 = mag;
  const float* m1 = mag + (size_t)K_DIM * N_DIM;
  const float* m2 = mag + 2 * (size_t)K_DIM * N_DIM;

  float s = 0.f, s2 = 0.f;
  #pragma unroll
  for (int rg = 0; rg < 4; ++rg) {
    int il = rg * 16 + lr;
    size_t base = (size_t)(i0 + il) * N_DIM + o0 + lc * 4;
    float4 a = *(const float4*)(m0 + base);
    float4 b = *(const float4*)(m1 + base);
    float4 c = *(const float4*)(m2 + base);
    float4 g = *(const float4*)(sgn + base);
    float w0 = wval(a.x, b.x, c.x, g.x);
    float w1 = wval(a.y, b.y, c.y, g.y);
    float w2 = wval(a.z, b.z, c.z, g.z);
    float w3 = wval(a.w, b.w, c.w, g.w);
    wl[il][lc * 4 + 0] = w0;
    wl[il][lc * 4 + 1] = w1;
    wl[il][lc * 4 + 2] = w2;
    wl[il][lc * 4 + 3] = w3;
    s  += w0 + w1 + w2 + w3;
    s2 += w0 * w0 + w1 * w1 + w2 * w2 + w3 * w3;
  }
  // deterministic per-block reduction (no float atomics -> replay-stable)
  #pragma unroll
  for (int off = 32; off > 0; off >>= 1) {
    s  += __shfl_down(s,  off);
    s2 += __shfl_down(s2, off);
  }
  if ((tid & 63) == 0) { parts[tid >> 6] = s; parts[4 + (tid >> 6)] = s2; }
  __syncthreads();
  if (tid == 0) {
    int bid = blockIdx.y * gridDim.x + blockIdx.x;
    psum[bid]   = parts[0] + parts[1] + parts[2] + parts[3];
    psumsq[bid] = parts[4] + parts[5] + parts[6] + parts[7];
  }
  // transposed coalesced write: Wt[o][i]
  #pragma unroll
  for (int rg = 0; rg < 4; ++rg) {
    int ol = rg * 16 + lr;
    int il = lc * 4;
    ushort4 v;
    v.x = f2bf(wl[il + 0][ol]);
    v.y = f2bf(wl[il + 1][ol]);
    v.z = f2bf(wl[il + 2][ol]);
    v.w = f2bf(wl[il + 3][ol]);
    *(ushort4*)(wt + (size_t)(o0 + ol) * K_DIM + i0 + il) = v;
  }
}

// ---------- Kernel 2: x f32 -> bf16 ----------
__global__ __launch_bounds__(256) void cvt_x(const float* __restrict__ x,
                                             uint16_t* __restrict__ xb, int n8)
{
  int idx = blockIdx.x * blockDim.x + threadIdx.x;
  int stride = gridDim.x * blockDim.x;
  for (; idx < n8; idx += stride) {
    float4 v0 = ((const float4*)x)[2 * idx];
    float4 v1 = ((const float4*)x)[2 * idx + 1];
    ushort4 r0, r1;
    r0.x = f2bf(v0.x); r0.y = f2bf(v0.y); r0.z = f2bf(v0.z); r0.w = f2bf(v0.w);
    r1.x = f2bf(v1.x); r1.y = f2bf(v1.y); r1.z = f2bf(v1.z); r1.w = f2bf(v1.w);
    ((ushort4*)xb)[2 * idx]     = r0;
    ((ushort4*)xb)[2 * idx + 1] = r1;
  }
}

// ---------- Kernel 3: alpha = std_target / (std(w) + eps) ----------
__global__ __launch_bounds__(256) void calc_alpha(const float* __restrict__ psum,
                                                  const float* __restrict__ psumsq,
                                                  float* __restrict__ alpha, int nparts)
{
  __shared__ float ls[256], lq[256];
  int tid = threadIdx.x;
  float s = 0.f, q = 0.f;
  for (int i = tid; i < nparts; i += 256) { s += psum[i]; q += psumsq[i]; }
  ls[tid] = s; lq[tid] = q;
  __syncthreads();
  for (int off = 128; off > 0; off >>= 1) {
    if (tid < off) { ls[tid] += ls[tid + off]; lq[tid] += lq[tid + off]; }
    __syncthreads();
  }
  if (tid == 0) {
    const float n = 16777216.f;
    float mean = ls[0] / n;
    float var  = lq[0] / n - mean * mean;
    var = var < 0.f ? 0.f : var;
    float stdv = sqrtf(var);
    alpha[0] = 0.022097086912079608f / (stdv + 1e-8f);  // sqrt(2/4096)/(std+eps)
  }
}

// ---------- Kernel 4: 256x256 uniform-phase bf16 MFMA GEMM (m201-exact) ----
// 8 waves (2m x 4n), wave C = 128x64 (8x4 frags 16x16x32), BK=64.
// LDS 128 KiB: 2 buffers x [256 rows][128B] per matrix; zero-conflict swizzle
// LDS[row][cb] = global[..][cb ^ ((row&7)<<4)] (verified R1/R3/R4/R5).
// 4 uniform phases per K-tile u (quadrants Q00,Q01,Q10,Q11). Each phase:
//   { stage 1 half-tile (2 gloads); vmcnt(12); bar; lgkmcnt(0);
//     issue NEXT subtile's ds_reads (4 or 8 b128, one phase ahead of use);
//     setprio(1); 16 MFMA; setprio(0); bar }
// Read schedule (1 phase ahead): p0->B1(u), p1->A1(u), p2->A0(u+1), p3->B0(u+1).
// Stage schedule into buf[u&1] (tile u+2): p0->A0, p1->B0, p2->B1, p3->A1
//   (each slot provably free: its reads drained by lgkm0 + >=1 barrier earlier).
// vmcnt(12) = 6 half-tiles in flight; retire arithmetic: each half retires at
// exactly the phase that reads it. Tail: k-indices clamp (harmless re-fetch,
// data never used) so the loop is branch-free and counts stay uniform.
__global__ __launch_bounds__(512, 2) void gemm_bf16_u4(
    const uint16_t* __restrict__ xb, const uint16_t* __restrict__ wt,
    const float* __restrict__ alphap, float* __restrict__ out)
{
  __shared__ __align__(16) unsigned char sA[2][256 * 128];
  __shared__ __align__(16) unsigned char sB[2][256 * 128];

  const int tid  = threadIdx.x;
  const int lane = tid & 63;
  const int wv   = tid >> 6;        // 0..7
  const int wm   = wv >> 2;         // 0..1
  const int wn   = wv & 3;          // 0..3

  // XCD-aware bijective swizzle: 512 blocks = 8 regions of 8x8
  const int bid = blockIdx.x;
  const int xcd = bid & 7;
  const int c   = bid >> 3;                  // 0..63
  const int bm  = (xcd >> 1) * 8 + (c >> 3); // 0..31
  const int bn  = (xcd & 1) * 8 + (c & 7);   // 0..15

  const size_t rowA0 = (size_t)bm * 256;
  const size_t rowB0 = (size_t)bn * 256;

  f32x4 acc[8][4] = {};

  const int l15   = lane & 15;
  const int src_x = ((lane & 7) ^ (lane >> 3)) << 4;            // staging source pre-swizzle
  const int cb0   = (((lane >> 4) << 4)) ^ ((lane & 7) << 4);   // kk=0 read col-bytes
  const int cb1   = (64 | ((lane >> 4) << 4)) ^ ((lane & 7) << 4);

#define STA(cc, mh, h, kt)                                                          \
  gload16((const char*)xb + (((rowA0 + (h) * 128 + (mh) * 64 + wv * 8 + (lane >> 3)) \
              * (size_t)K_DIM + (size_t)(kt) * 64) << 1) + src_x,                   \
          &sA[cc][((mh) * 128 + (h) * 64 + wv * 8) * 128])
#define STB(cc, bh, h, kt)                                                          \
  gload16((const char*)wt + (((rowB0 + (2 * (h) + (wv >> 2)) * 64 + (bh) * 32       \
              + (wv & 3) * 8 + (lane >> 3)) * (size_t)K_DIM + (size_t)(kt) * 64) << 1) + src_x, \
          &sB[cc][((bh) * 128 + (h) * 64 + wv * 8) * 128])
#define STAGE_A(cc, mh, kt) do { STA(cc, mh, 0, kt); STA(cc, mh, 1, kt); } while (0)
#define STAGE_B(cc, bh, kt) do { STB(cc, bh, 0, kt); STB(cc, bh, 1, kt); } while (0)

#define LDA8(Ap, mh, dst) do { _Pragma("unroll")                                    \
  for (int m = 0; m < 4; ++m) {                                                     \
    const unsigned char* rp = (Ap) + (size_t)((mh) * 128 + wm * 64 + m * 16 + l15) * 128; \
    dst[2 * m]     = *(const bf16x8*)(rp + cb0);                                    \
    dst[2 * m + 1] = *(const bf16x8*)(rp + cb1); } } while (0)
#define LDB4(Bp, bh, dst) do { _Pragma("unroll")                                    \
  for (int n = 0; n < 2; ++n) {                                                     \
    const unsigned char* rp = (Bp) + (size_t)((bh) * 128 + wn * 32 + n * 16 + l15) * 128; \
    dst[2 * n]     = *(const bf16x8*)(rp + cb0);                                    \
    dst[2 * n + 1] = *(const bf16x8*)(rp + cb1); } } while (0)

#define MMQ(AF, BF, mh, bh) do {                                                    \
  __builtin_amdgcn_s_setprio(1);                                                    \
  _Pragma("unroll") for (int m = 0; m < 4; ++m)                                     \
    _Pragma("unroll") for (int n = 0; n < 2; ++n) {                                 \
      acc[(mh)*4+m][(bh)*2+n] = __builtin_amdgcn_mfma_f32_16x16x32_bf16(            \
          AF[2*m],   BF[2*n],   acc[(mh)*4+m][(bh)*2+n], 0, 0, 0);                  \
      acc[(mh)*4+m][(bh)*2+n] = __builtin_amdgcn_mfma_f32_16x16x32_bf16(            \
          AF[2*m+1], BF[2*n+1], acc[(mh)*4+m][(bh)*2+n], 0, 0, 0); }                \
  __builtin_amdgcn_s_setprio(0); } while (0)

#define SCHED0   __builtin_amdgcn_sched_barrier(0)
#define LGKM0    do { asm volatile("s_waitcnt lgkmcnt(0)" ::: "memory"); SCHED0; } while (0)
#define WAITV(N) do { asm volatile("s_waitcnt vmcnt(" #N ")"   ::: "memory"); SCHED0; } while (0)
#define BAR      do { asm volatile("s_barrier" ::: "memory"); SCHED0; } while (0)

  bf16x8 A0f[8], A1f[8], B0f[4], B1f[4];

  // ---- prologue: emulate tiles u=-2,-1 of the steady-state pipeline ----
  // t0 halves in issue order A0,B0,B1,A1; t1 halves A0,B0 (then B1,A1 after reads)
  STAGE_A(0, 0, 0); STAGE_B(0, 0, 0); STAGE_B(0, 1, 0); STAGE_A(0, 1, 0);
  STAGE_A(1, 0, 1); STAGE_B(1, 0, 1);
  WAITV(8);   // 12 outstanding -> retire t0's A0,B0
  BAR;
  LDA8(sA[0], 0, A0f); LDB4(sB[0], 0, B0f); SCHED0;   // reads of tile 0 (drained at u=0 p0)
  STAGE_B(1, 1, 1); STAGE_A(1, 1, 1);                 // t1's B1,A1 (=-1p2,-1p3 stages)

  #pragma unroll 1
  for (int u = 0; u < 64; ++u) {
    const int cc = u & 1, oc = cc ^ 1;
    const unsigned char* Acur = sA[cc];
    const unsigned char* Bcur = sB[cc];
    const unsigned char* Aoth = sA[oc];
    const unsigned char* Both = sB[oc];
    const int k2 = (u + 2 < 64) ? (u + 2) : 63;   // clamped: tail re-stages, data unused
    // (tail reads of "tile 64" also clamp via Aoth/Both slots: garbage regs, never used)

    // ---- p0: Q00 ----
    STAGE_A(cc, 0, k2);
    WAITV(12); BAR; LGKM0;
    LDB4(Bcur, 1, B1f); SCHED0;               // hidden under Q00 (4 b128)
    MMQ(A0f, B0f, 0, 0); SCHED0;
    BAR;

    // ---- p1: Q01 ----
    STAGE_B(cc, 0, k2);
    WAITV(12); BAR; LGKM0;
    LDA8(Acur, 1, A1f); SCHED0;               // hidden under Q01 (8 b128)
    MMQ(A0f, B1f, 0, 1); SCHED0;
    BAR;

    // ---- p2: Q10 ----
    STAGE_B(cc, 1, k2);
    WAITV(12); BAR; LGKM0;
    LDA8(Aoth, 0, A0f); SCHED0;               // next tile's A0 (8 b128) under Q10
    MMQ(A1f, B0f, 1, 0); SCHED0;
    BAR;

    // ---- p3: Q11 ----
    STAGE_A(cc, 1, k2);
    WAITV(12); BAR; LGKM0;
    LDB4(Both, 0, B0f); SCHED0;               // next tile's B0 (4 b128) under Q11
    MMQ(A1f, B1f, 1, 1); SCHED0;
    BAR;
  }

#undef STA
#undef STB
#undef STAGE_A
#undef STAGE_B
#undef LDA8
#undef LDB4
#undef MMQ
#undef SCHED0
#undef LGKM0
#undef WAITV
#undef BAR

  const float alpha = alphap[0];
  const int ccol  = bn * 256 + wn * 64 + l15;
  const int crow0 = bm * 256 + wm * 128 + ((lane >> 4) << 2);
  #pragma unroll
  for (int am = 0; am < 8; ++am)
    #pragma unroll
    for (int an = 0; an < 4; ++an)
      #pragma unroll
      for (int r = 0; r < 4; ++r)
        out[(size_t)(crow0 + am * 16 + r) * N_DIM + ccol + an * 16] = acc[am][an][r] * alpha;
}

extern "C" void kernel_launch(void* const* d_in, const int* in_sizes, int n_in,
                              void* d_out, int out_size, void* d_ws, size_t ws_size,
                              hipStream_t stream) {
  const float* x   = (const float*)d_in[0];
  const float* mag = (const float*)d_in[1];
  const float* sgn = (const float*)d_in[2];
  float* out = (float*)d_out;

  char* ws = (char*)d_ws;
  float* alpha    = (float*)ws;
  float* psum     = (float*)(ws + 256);
  float* psumsq   = (float*)(ws + 256 + 16384);
  uint16_t* wt    = (uint16_t*)(ws + 256 + 32768);
  uint16_t* xb    = (uint16_t*)(ws + 256 + 32768 + 33554432ull);
  size_t needed = 256 + 32768 + 33554432ull + 67108864ull;
  if (ws_size < needed) return;

  build_wt<<<dim3(64, 64), 256, 0, stream>>>(mag, sgn, wt, psum, psumsq);
  cvt_x<<<dim3(2048), 256, 0, stream>>>(x, xb, (M_DIM * K_DIM) / 8);
  calc_alpha<<<dim3(1), 256, 0, stream>>>(psum, psumsq, alpha, 4096);
  gemm_bf16_u4<<<dim3(512), 512, 0, stream>>>(xb, wt, alpha, out);
}

// Round 7
// 329.699 us; speedup vs baseline: 1.2268x; 1.2268x over previous
//
#include <hip/hip_runtime.h>
#include <hip/hip_bf16.h>
#include <stdint.h>

#define K_DIM 4096
#define M_DIM 8192
#define N_DIM 4096

typedef short bf16x8 __attribute__((ext_vector_type(8)));
typedef float f32x4  __attribute__((ext_vector_type(4)));

__device__ __forceinline__ uint16_t f2bf(float f) {
  uint32_t u = __float_as_uint(f);
  u += 0x7fffu + ((u >> 16) & 1u);   // round-to-nearest-even
  return (uint16_t)(u >> 16);
}

__device__ __forceinline__ float wval(float b0, float b1, float b2, float sg) {
  float mg = (b0 >= 0.f ? 0.5f : 0.f) + (b1 >= 0.f ? 0.25f : 0.f) + (b2 >= 0.f ? 0.125f : 0.f);
  return (sg >= 0.f) ? mg : -mg;
}

__device__ __forceinline__ void gload16(const void* g, void* l) {
  typedef __attribute__((address_space(1))) const uint32_t gu32;
  typedef __attribute__((address_space(3))) uint32_t lu32;
  __builtin_amdgcn_global_load_lds((gu32*)g, (lu32*)l, 16, 0, 0);
}

// ---------- Kernel 1: W^T (bf16) build + transpose + per-block sum/sumsq ----
__global__ __launch_bounds__(256) void build_wt(
    const float* __restrict__ mag, const float* __restrict__ sgn,
    uint16_t* __restrict__ wt, float* __restrict__ psum, float* __restrict__ psumsq)
{
  __shared__ float wl[64][65];
  __shared__ float parts[8];
  const int tid = threadIdx.x;
  const int lr = tid >> 4;   // 0..15
  const int lc = tid & 15;   // 0..15
  const int i0 = blockIdx.y * 64;   // input-dim (K) tile
  const int o0 = blockIdx.x * 64;   // output-dim (N) tile
  const float* m0 = mag;
  const float* m1 = mag + (size_t)K_DIM * N_DIM;
  const float* m2 = mag + 2 * (size_t)K_DIM * N_DIM;

  float s = 0.f, s2 = 0.f;
  #pragma unroll
  for (int rg = 0; rg < 4; ++rg) {
    int il = rg * 16 + lr;
    size_t base = (size_t)(i0 + il) * N_DIM + o0 + lc * 4;
    float4 a = *(const float4*)(m0 + base);
    float4 b = *(const float4*)(m1 + base);
    float4 c = *(const float4*)(m2 + base);
    float4 g = *(const float4*)(sgn + base);
    float w0 = wval(a.x, b.x, c.x, g.x);
    float w1 = wval(a.y, b.y, c.y, g.y);
    float w2 = wval(a.z, b.z, c.z, g.z);
    float w3 = wval(a.w, b.w, c.w, g.w);
    wl[il][lc * 4 + 0] = w0;
    wl[il][lc * 4 + 1] = w1;
    wl[il][lc * 4 + 2] = w2;
    wl[il][lc * 4 + 3] = w3;
    s  += w0 + w1 + w2 + w3;
    s2 += w0 * w0 + w1 * w1 + w2 * w2 + w3 * w3;
  }
  // deterministic per-block reduction (no float atomics -> replay-stable)
  #pragma unroll
  for (int off = 32; off > 0; off >>= 1) {
    s  += __shfl_down(s,  off);
    s2 += __shfl_down(s2, off);
  }
  if ((tid & 63) == 0) { parts[tid >> 6] = s; parts[4 + (tid >> 6)] = s2; }
  __syncthreads();
  if (tid == 0) {
    int bid = blockIdx.y * gridDim.x + blockIdx.x;
    psum[bid]   = parts[0] + parts[1] + parts[2] + parts[3];
    psumsq[bid] = parts[4] + parts[5] + parts[6] + parts[7];
  }
  // transposed coalesced write: Wt[o][i]
  #pragma unroll
  for (int rg = 0; rg < 4; ++rg) {
    int ol = rg * 16 + lr;
    int il = lc * 4;
    ushort4 v;
    v.x = f2bf(wl[il + 0][ol]);
    v.y = f2bf(wl[il + 1][ol]);
    v.z = f2bf(wl[il + 2][ol]);
    v.w = f2bf(wl[il + 3][ol]);
    *(ushort4*)(wt + (size_t)(o0 + ol) * K_DIM + i0 + il) = v;
  }
}

// ---------- Kernel 2: x f32 -> bf16 ----------
__global__ __launch_bounds__(256) void cvt_x(const float* __restrict__ x,
                                             uint16_t* __restrict__ xb, int n8)
{
  int idx = blockIdx.x * blockDim.x + threadIdx.x;
  int stride = gridDim.x * blockDim.x;
  for (; idx < n8; idx += stride) {
    float4 v0 = ((const float4*)x)[2 * idx];
    float4 v1 = ((const float4*)x)[2 * idx + 1];
    ushort4 r0, r1;
    r0.x = f2bf(v0.x); r0.y = f2bf(v0.y); r0.z = f2bf(v0.z); r0.w = f2bf(v0.w);
    r1.x = f2bf(v1.x); r1.y = f2bf(v1.y); r1.z = f2bf(v1.z); r1.w = f2bf(v1.w);
    ((ushort4*)xb)[2 * idx]     = r0;
    ((ushort4*)xb)[2 * idx + 1] = r1;
  }
}

// ---------- Kernel 3: alpha = std_target / (std(w) + eps) ----------
__global__ __launch_bounds__(256) void calc_alpha(const float* __restrict__ psum,
                                                  const float* __restrict__ psumsq,
                                                  float* __restrict__ alpha, int nparts)
{
  __shared__ float ls[256], lq[256];
  int tid = threadIdx.x;
  float s = 0.f, q = 0.f;
  for (int i = tid; i < nparts; i += 256) { s += psum[i]; q += psumsq[i]; }
  ls[tid] = s; lq[tid] = q;
  __syncthreads();
  for (int off = 128; off > 0; off >>= 1) {
    if (tid < off) { ls[tid] += ls[tid + off]; lq[tid] += lq[tid + off]; }
    __syncthreads();
  }
  if (tid == 0) {
    const float n = 16777216.f;
    float mean = ls[0] / n;
    float var  = lq[0] / n - mean * mean;
    var = var < 0.f ? 0.f : var;
    float stdv = sqrtf(var);
    alpha[0] = 0.022097086912079608f / (stdv + 1e-8f);  // sqrt(2/4096)/(std+eps)
  }
}

// ---------- Kernel 4: 256x256 bf16 GEMM, 1 barrier/phase + read-ahead ------
// 8 waves (2m x 4n), wave C = 128x64 (8x4 frags 16x16x32), BK=64, 2 LDS bufs.
// Zero-conflict swizzle LDS[row][cb]=global[..][cb ^ ((row&7)<<4)] (R1/R3/R4).
// Phase p section: { stage 1 half; [p3: vmcnt(4)]; BAR; lgkmcnt0+sched0;
//                    MFMA quadrant; issue NEXT quadrant's ds_reads }
// Read-issue (post-MFMA, drain at next LGKM0 -> LDS pipe runs under MFMA):
//   p3 -> A0,B0(next tile), p0 -> B1(cur), p1 -> A1(cur), p2 -> none.
// Stage schedule (slot q >= last-drain r + 2 phases, 1 barrier separates):
//   p0: B1(u+1,oc) [B1(oc) drained u-1 p1]   p1: A1(u+1,oc) [drained u-1 p2]
//   p2: A0(u+2,cc) [drained u p0]            p3: B0(u+2,cc) [drained u p0]
// Certification: per-wave WAITV(4)@p3 + BAR => stages <= p1 globally visible;
// every read's source verified staged <= the covering p1 (see derivation).
// Tail: k clamps (re-stage of live/garbage slots is provably safe & unused).
__global__ __launch_bounds__(512, 2) void gemm_bf16_v7(
    const uint16_t* __restrict__ xb, const uint16_t* __restrict__ wt,
    const float* __restrict__ alphap, float* __restrict__ out)
{
  __shared__ __align__(16) unsigned char sA[2][256 * 128];
  __shared__ __align__(16) unsigned char sB[2][256 * 128];

  const int tid  = threadIdx.x;
  const int lane = tid & 63;
  const int wv   = tid >> 6;        // 0..7
  const int wm   = wv >> 2;         // 0..1
  const int wn   = wv & 3;          // 0..3

  // XCD-aware bijective swizzle: 512 blocks = 8 regions of 8x8
  const int bid = blockIdx.x;
  const int xcd = bid & 7;
  const int c   = bid >> 3;                  // 0..63
  const int bm  = (xcd >> 1) * 8 + (c >> 3); // 0..31
  const int bn  = (xcd & 1) * 8 + (c & 7);   // 0..15

  const size_t rowA0 = (size_t)bm * 256;
  const size_t rowB0 = (size_t)bn * 256;

  f32x4 acc[8][4] = {};

  const int l15   = lane & 15;
  const int src_x = ((lane & 7) ^ (lane >> 3)) << 4;            // staging source pre-swizzle
  const int cb0   = (((lane >> 4) << 4)) ^ ((lane & 7) << 4);   // kk=0 read col-bytes
  const int cb1   = (64 | ((lane >> 4) << 4)) ^ ((lane & 7) << 4);

#define STA(cc_, mh, h, kt)                                                         \
  gload16((const char*)xb + (((rowA0 + (h) * 128 + (mh) * 64 + wv * 8 + (lane >> 3)) \
              * (size_t)K_DIM + (size_t)(kt) * 64) << 1) + src_x,                   \
          &sA[cc_][((mh) * 128 + (h) * 64 + wv * 8) * 128])
#define STB(cc_, bh, h, kt)                                                         \
  gload16((const char*)wt + (((rowB0 + (2 * (h) + (wv >> 2)) * 64 + (bh) * 32       \
              + (wv & 3) * 8 + (lane >> 3)) * (size_t)K_DIM + (size_t)(kt) * 64) << 1) + src_x, \
          &sB[cc_][((bh) * 128 + (h) * 64 + wv * 8) * 128])
#define STAGE_A(cc_, mh, kt) do { STA(cc_, mh, 0, kt); STA(cc_, mh, 1, kt); } while (0)
#define STAGE_B(cc_, bh, kt) do { STB(cc_, bh, 0, kt); STB(cc_, bh, 1, kt); } while (0)

#define LDA8(Ap, mh, dst) do { _Pragma("unroll")                                    \
  for (int m = 0; m < 4; ++m) {                                                     \
    const unsigned char* rp = (Ap) + (size_t)((mh) * 128 + wm * 64 + m * 16 + l15) * 128; \
    dst[2 * m]     = *(const bf16x8*)(rp + cb0);                                    \
    dst[2 * m + 1] = *(const bf16x8*)(rp + cb1); } } while (0)
#define LDB4(Bp, bh, dst) do { _Pragma("unroll")                                    \
  for (int n = 0; n < 2; ++n) {                                                     \
    const unsigned char* rp = (Bp) + (size_t)((bh) * 128 + wn * 32 + n * 16 + l15) * 128; \
    dst[2 * n]     = *(const bf16x8*)(rp + cb0);                                    \
    dst[2 * n + 1] = *(const bf16x8*)(rp + cb1); } } while (0)

#define MMQ(AF, BF, mh, bh) do {                                                    \
  __builtin_amdgcn_s_setprio(1);                                                    \
  _Pragma("unroll") for (int m = 0; m < 4; ++m)                                     \
    _Pragma("unroll") for (int n = 0; n < 2; ++n) {                                 \
      acc[(mh)*4+m][(bh)*2+n] = __builtin_amdgcn_mfma_f32_16x16x32_bf16(            \
          AF[2*m],   BF[2*n],   acc[(mh)*4+m][(bh)*2+n], 0, 0, 0);                  \
      acc[(mh)*4+m][(bh)*2+n] = __builtin_amdgcn_mfma_f32_16x16x32_bf16(            \
          AF[2*m+1], BF[2*n+1], acc[(mh)*4+m][(bh)*2+n], 0, 0, 0); }                \
  __builtin_amdgcn_s_setprio(0); } while (0)

#define SCHED0   __builtin_amdgcn_sched_barrier(0)
#define LGKM0    do { asm volatile("s_waitcnt lgkmcnt(0)" ::: "memory"); SCHED0; } while (0)
#define WAITV(N) do { asm volatile("s_waitcnt vmcnt(" #N ")"   ::: "memory"); SCHED0; } while (0)
#define BAR      do { asm volatile("s_barrier" ::: "memory"); SCHED0; } while (0)

  bf16x8 A0f[8], A1f[8], B0f[4], B1f[4];

  // ---- prologue (= steady-state state at entry of u=0 p0) ----
  // issue order matches steady vmcnt arithmetic: tile0 {A0,B0,B1,A1}, tile1 {A0,B0}
  STAGE_A(0, 0, 0); STAGE_B(0, 0, 0); STAGE_B(0, 1, 0); STAGE_A(0, 1, 0);
  STAGE_A(1, 0, 1); STAGE_B(1, 0, 1);
  WAITV(4);                       // drain tile0 fully (tile1 A0,B0 may fly)
  BAR;
  LDA8(sA[0], 0, A0f); LDB4(sB[0], 0, B0f); SCHED0;   // tile0 A0,B0 reads

  #pragma unroll 1
  for (int u = 0; u < 64; ++u) {
    const int cc = u & 1, oc = cc ^ 1;
    const unsigned char* Acur = sA[cc];
    const unsigned char* Bcur = sB[cc];
    const unsigned char* Aoth = sA[oc];
    const unsigned char* Both = sB[oc];
    const int k1 = (u + 1 < 64) ? (u + 1) : 63;   // clamped tail (safe, unused)
    const int k2 = (u + 2 < 64) ? (u + 2) : 63;

    // ---- p0: Q00 ----
    STAGE_B(oc, 1, k1);            // B1(u+1); slot drained at u-1 p1
    BAR; LGKM0;
    MMQ(A0f, B0f, 0, 0);
    LDB4(Bcur, 1, B1f); SCHED0;    // B1(u) reads, drain at p1's LGKM0

    // ---- p1: Q01 ----
    STAGE_A(oc, 1, k1);            // A1(u+1); slot drained at u-1 p2
    BAR; LGKM0;
    MMQ(A0f, B1f, 0, 1);
    LDA8(Acur, 1, A1f); SCHED0;    // A1(u) reads, drain at p2's LGKM0

    // ---- p2: Q10 ----
    STAGE_A(cc, 0, k2);            // A0(u+2); slot drained at u p0
    BAR; LGKM0;
    MMQ(A1f, B0f, 1, 0);

    // ---- p3: Q11 ----
    STAGE_B(cc, 0, k2);            // B0(u+2); slot drained at u p0
    WAITV(4);                      // certify stages <= u p1 (with BAR below)
    BAR; LGKM0;
    MMQ(A1f, B1f, 1, 1);
    LDA8(Aoth, 0, A0f); LDB4(Both, 0, B0f); SCHED0;   // next tile A0,B0
  }

#undef STA
#undef STB
#undef STAGE_A
#undef STAGE_B
#undef LDA8
#undef LDB4
#undef MMQ
#undef SCHED0
#undef LGKM0
#undef WAITV
#undef BAR

  const float alpha = alphap[0];
  const int ccol  = bn * 256 + wn * 64 + l15;
  const int crow0 = bm * 256 + wm * 128 + ((lane >> 4) << 2);
  #pragma unroll
  for (int am = 0; am < 8; ++am)
    #pragma unroll
    for (int an = 0; an < 4; ++an)
      #pragma unroll
      for (int r = 0; r < 4; ++r)
        out[(size_t)(crow0 + am * 16 + r) * N_DIM + ccol + an * 16] = acc[am][an][r] * alpha;
}

extern "C" void kernel_launch(void* const* d_in, const int* in_sizes, int n_in,
                              void* d_out, int out_size, void* d_ws, size_t ws_size,
                              hipStream_t stream) {
  const float* x   = (const float*)d_in[0];
  const float* mag = (const float*)d_in[1];
  const float* sgn = (const float*)d_in[2];
  float* out = (float*)d_out;

  char* ws = (char*)d_ws;
  float* alpha    = (float*)ws;
  float* psum     = (float*)(ws + 256);
  float* psumsq   = (float*)(ws + 256 + 16384);
  uint16_t* wt    = (uint16_t*)(ws + 256 + 32768);
  uint16_t* xb    = (uint16_t*)(ws + 256 + 32768 + 33554432ull);
  size_t needed = 256 + 32768 + 33554432ull + 67108864ull;
  if (ws_size < needed) return;

  build_wt<<<dim3(64, 64), 256, 0, stream>>>(mag, sgn, wt, psum, psumsq);
  cvt_x<<<dim3(2048), 256, 0, stream>>>(x, xb, (M_DIM * K_DIM) / 8);
  calc_alpha<<<dim3(1), 256, 0, stream>>>(psum, psumsq, alpha, 4096);
  gemm_bf16_v7<<<dim3(512), 512, 0, stream>>>(xb, wt, alpha, out);
}